// Round 14
// baseline (160.803 us; speedup 1.0000x reference)
//
#include <hip/hip_runtime.h>
#include <hip/hip_bf16.h>
#include <stdint.h>

#define Bb 8
#define Ss 2048
#define Dd 4096
#define Ee 64
#define CAP 40
#define M_TOK (Bb*Ss)                    // 16384 tokens
#define TOP1_OFF  (M_TOK*Ee)             // 1048576
#define PROBS_OFF (TOP1_OFF + M_TOK)     // 1064960
#define AUX_OFF   (PROBS_OFF + M_TOK*Ee) // 2113536
#define ND_OFF    (AUX_OFF + 1)

// ws byte offsets
#define W2_OFF   0u                      // 1 MB chunk-major W hi/lo
#define PART_OFF (1u<<20)                // 16 MB fp32 partials [tg][ks4][64][64]
#define CNTT_OFF (17u<<20)               // 64 KB int   cntT[b][e][32]
#define PIT_OFF  ((17u<<20) + (64u<<10)) // 64 KB float piT [b][e][32]
#define EID_OFF  ((17u<<20) + (128u<<10))// 64 KB int   eid[tok]

typedef __attribute__((ext_vector_type(8))) short short8;
typedef __attribute__((ext_vector_type(4))) float f32x4;

// pin vmem issue order across this point (IR + MIR schedulers)
#define FENCE() do {                                                          \
    asm volatile("" ::: "memory");                                            \
    __builtin_amdgcn_sched_barrier(0);                                        \
  } while (0)

__device__ __forceinline__ void cvt8hl(const float4 a, const float4 b,
                                       short8& hi, short8& lo) {
  __hip_bfloat162 h0 = __float22bfloat162_rn(make_float2(a.x, a.y));
  __hip_bfloat162 h1 = __float22bfloat162_rn(make_float2(a.z, a.w));
  __hip_bfloat162 h2 = __float22bfloat162_rn(make_float2(b.x, b.y));
  __hip_bfloat162 h3 = __float22bfloat162_rn(make_float2(b.z, b.w));
  float2 f0 = __bfloat1622float2(h0), f1 = __bfloat1622float2(h1);
  float2 f2 = __bfloat1622float2(h2), f3 = __bfloat1622float2(h3);
  __hip_bfloat162 l0 = __float22bfloat162_rn(make_float2(a.x - f0.x, a.y - f0.y));
  __hip_bfloat162 l1 = __float22bfloat162_rn(make_float2(a.z - f1.x, a.w - f1.y));
  __hip_bfloat162 l2 = __float22bfloat162_rn(make_float2(b.x - f2.x, b.y - f2.y));
  __hip_bfloat162 l3 = __float22bfloat162_rn(make_float2(b.z - f3.x, b.w - f3.y));
  union U { __hip_bfloat162 h[4]; short8 s; };
  U uh; uh.h[0] = h0; uh.h[1] = h1; uh.h[2] = h2; uh.h[3] = h3; hi = uh.s;
  U ul; ul.h[0] = l0; ul.h[1] = l1; ul.h[2] = l2; ul.h[3] = l3; lo = ul.s;
}

// ---- k0: W [k][e] fp32 -> chunk-major hi/lo bf16 fragments -----------------
// k32-chunk C at byte C*8192: [g(4)][hl(2)][lane(64)x16B]
__global__ __launch_bounds__(256) void k0_wsplit(const float* __restrict__ W,
                                                 char* __restrict__ w2) {
  const int id  = blockIdx.x * 256 + threadIdx.x;   // 32768 items
  const int l   = id & 63;
  const int g   = (id >> 6) & 3;
  const int sub = (id >> 8) & 1;
  const int c   = id >> 9;
  const int e   = g * 16 + (l & 15);
  const int kb  = c * 64 + sub * 32 + (l >> 4) * 8;
  float xs[8];
#pragma unroll
  for (int j = 0; j < 8; ++j) xs[j] = W[(size_t)(kb + j) * Ee + e];
  short8 hi, lo;
  cvt8hl(make_float4(xs[0], xs[1], xs[2], xs[3]),
         make_float4(xs[4], xs[5], xs[6], xs[7]), hi, lo);
  char* base = w2 + (size_t)c * 16384 + sub * 8192 + g * 2048 + l * 16;
  *(short8*)base = hi;
  *(short8*)(base + 1024) = lo;
}

// ---- k1: barrier-free 64-token x K-quarter MFMA partial GEMM ---------------
// grid 1024: tg = bid>>2, ks = bid&3 (XCD = bid%8 -> W-quarter L2-resident).
// Wave = 16 tokens x ALL 64 experts x k-quarter. W held in REGISTERS
// (8 short8 per chunk, double-buffered); the 4 waves of a block read the
// same 8 KB W chunk (L1 dedup). NO LDS, NO barriers -- waves independent.
// vmcnt ledger (issue order pinned by FENCE):
//   enter t: {LDA(t)=2, LDW(t)=8, LDA(t+1)=2}; wait vmcnt(2) retires
//   LDA(t)+LDW(t); then issue LDW(t+1)+LDA(t+2). Tails: t=30 same, t=31 -> 0.
__global__ __launch_bounds__(256, 4) void k1_gemm(
    const float* __restrict__ H, const char* __restrict__ w2,
    float* __restrict__ part) {
  const int tid = threadIdx.x;
  const int wv = tid >> 6, l = tid & 63;
  const int tg = blockIdx.x >> 2, ks = blockIdx.x & 3;
  const float* hA = H + (size_t)(tg * 64 + wv * 16 + (l & 15)) * Dd
                      + ks * 1024 + (l >> 4) * 8;
  const char* wsrc = w2 + (size_t)ks * 262144 + l * 16;

  f32x4 acc[4];
#pragma unroll
  for (int g = 0; g < 4; ++g) acc[g] = (f32x4){0.f, 0.f, 0.f, 0.f};

  float4 aX0, aX1, aY0, aY1;                       // depth-2 A prefetch
  short8 ah0, al0;
  short8 wa0, wa1, wa2, wa3, wa4, wa5, wa6, wa7;   // W buffer A (g0h..g3l)
  short8 wb0, wb1, wb2, wb3, wb4, wb5, wb6, wb7;   // W buffer B

#define LDA(r0, r1, t) { const float* p_ = hA + (t) * 32;                     \
    r0 = *(const float4*)(p_); r1 = *(const float4*)(p_ + 4); }

#define LDW(q0, q1, q2, q3, q4, q5, q6, q7, t) {                              \
    const char* p_ = wsrc + (size_t)(t) * 8192;                               \
    q0 = *(const short8*)(p_);        q1 = *(const short8*)(p_ + 1024);       \
    q2 = *(const short8*)(p_ + 2048); q3 = *(const short8*)(p_ + 3072);       \
    q4 = *(const short8*)(p_ + 4096); q5 = *(const short8*)(p_ + 5120);       \
    q6 = *(const short8*)(p_ + 6144); q7 = *(const short8*)(p_ + 7168); }

#define MFMA4(ac, ah, al, wh, wl) {                                           \
    ac = __builtin_amdgcn_mfma_f32_16x16x32_bf16(ah, wh, ac, 0, 0, 0);        \
    ac = __builtin_amdgcn_mfma_f32_16x16x32_bf16(ah, wl, ac, 0, 0, 0);        \
    ac = __builtin_amdgcn_mfma_f32_16x16x32_bf16(al, wh, ac, 0, 0, 0);        \
    ac = __builtin_amdgcn_mfma_f32_16x16x32_bf16(al, wl, ac, 0, 0, 0); }

  // ITER: wait -> cvt A(t) -> prefetch W(t+1), A(t+2) -> 16 MFMA on W(t)
#define ITER(aU0, aU1, c0, c1, c2, c3, c4, c5, c6, c7,                        \
             n0, n1, n2, n3, n4, n5, n6, n7, t) {                             \
    if ((t) == 31) { asm volatile("s_waitcnt vmcnt(0)" ::: "memory"); }       \
    else           { asm volatile("s_waitcnt vmcnt(2)" ::: "memory"); }       \
    FENCE();                                                                  \
    cvt8hl(aU0, aU1, ah0, al0);                                               \
    FENCE();                                                                  \
    if ((t) < 31) LDW(n0, n1, n2, n3, n4, n5, n6, n7, (t) + 1);               \
    if ((t) < 30) LDA(aU0, aU1, (t) + 2);                                     \
    FENCE();                                                                  \
    MFMA4(acc[0], ah0, al0, c0, c1);                                          \
    MFMA4(acc[1], ah0, al0, c2, c3);                                          \
    MFMA4(acc[2], ah0, al0, c4, c5);                                          \
    MFMA4(acc[3], ah0, al0, c6, c7); }

  // prologue: queue (oldest first) = LDA(0)[2], LDW(0)[8], LDA(1)[2]
  LDA(aX0, aX1, 0);
  FENCE();
  LDW(wa0, wa1, wa2, wa3, wa4, wa5, wa6, wa7, 0);
  FENCE();
  LDA(aY0, aY1, 1);
  FENCE();

#pragma unroll
  for (int cc = 0; cc < 16; ++cc) {
    ITER(aX0, aX1, wa0, wa1, wa2, wa3, wa4, wa5, wa6, wa7,
                   wb0, wb1, wb2, wb3, wb4, wb5, wb6, wb7, 2 * cc);
    ITER(aY0, aY1, wb0, wb1, wb2, wb3, wb4, wb5, wb6, wb7,
                   wa0, wa1, wa2, wa3, wa4, wa5, wa6, wa7, 2 * cc + 1);
  }

  // partial logits -> ws (fp32), [tg][ks][tok64][e]
  float* pp = part + (size_t)(tg * 4 + ks) * 4096;
#pragma unroll
  for (int g = 0; g < 4; ++g)
#pragma unroll
    for (int r = 0; r < 4; ++r)
      pp[(wv * 16 + (l >> 4) * 4 + r) * 64 + g * 16 + (l & 15)] = acc[g][r];
}

// ---- k1b: sum 4 k-partials + bias, softmax, argmax, chunk stats ------------
__global__ __launch_bounds__(512) void k1b_softmax(
    const float* __restrict__ part, const float* __restrict__ bias,
    float* __restrict__ out, int* __restrict__ cntT, float* __restrict__ piT,
    int* __restrict__ eid_ws) {
  __shared__ int   csh[512];
  __shared__ float psh[512];
  const int tid = threadIdx.x, wv = tid >> 6, l = tid & 63;
  const int tg = blockIdx.x;
  const float* p0 = part + (size_t)tg * 16384;

  int cnt = 0; float pis = 0.f;
  const float bl_ = bias[l];
#pragma unroll
  for (int i = 0; i < 8; ++i) {                 // wave owns 8 tokens
    const int t = wv * 8 + i, tok = tg * 64 + t;
    const float v = p0[t * 64 + l] + p0[4096 + t * 64 + l] +
                    p0[8192 + t * 64 + l] + p0[12288 + t * 64 + l] + bl_;
    float m = v; int mi = l;
#pragma unroll
    for (int off = 32; off >= 1; off >>= 1) {   // max + first-index argmax
      const float ov = __shfl_xor(m, off);
      const int   oi = __shfl_xor(mi, off);
      if (ov > m || (ov == m && oi < mi)) { m = ov; mi = oi; }
    }
    const float ex = __expf(v - m);
    float ssum = ex;
#pragma unroll
    for (int off = 32; off >= 1; off >>= 1) ssum += __shfl_xor(ssum, off);
    const float inv = 1.0f / ssum;
    const float p = ex * inv;
    out[(size_t)PROBS_OFF + (size_t)tok * Ee + l] = p;
    if (l == 0) {
      out[TOP1_OFF + tok] = inv;                // max prob = 1/sum
      eid_ws[tok] = mi;
    }
    cnt += (mi == l) ? 1 : 0;
    pis += p;
  }
  csh[wv * 64 + l] = cnt;
  psh[wv * 64 + l] = pis;
  __syncthreads();
  if (tid < 64) {
    int ct = 0; float pp = 0.f;
#pragma unroll
    for (int w = 0; w < 8; ++w) { ct += csh[w * 64 + tid]; pp += psh[w * 64 + tid]; }
    cntT[((size_t)(tg >> 5) * 64 + tid) * 32 + (tg & 31)] = ct;
    piT [((size_t)(tg >> 5) * 64 + tid) * 32 + (tg & 31)] = pp;
  }
}

// ---- k3: capacity mask (inline prefix) + one-hot write + aux/dropped -------
__global__ __launch_bounds__(64) void k3_indices(
    const int* __restrict__ cntT, const float* __restrict__ piT,
    const int* __restrict__ eid_ws, float* __restrict__ out) {
  __shared__ float tile[64][64];
  const int g = blockIdx.x, lane = threadIdx.x; // 64-token chunk
  const int b = g >> 5, cc = g & 31;
  const int tok = g * 64 + lane;
  const int e = eid_ws[tok];

  unsigned long long mymask = 0ull;             // same-expert mask in chunk
  for (int j = 0; j < 64; ++j) {
    const int ej = __shfl(e, j);
    const unsigned long long bal = __ballot(ej == e);
    if (j == lane) mymask = bal;
  }
  const int lrank = __popcll(mymask & ((1ull << lane) - 1ull));

  // prefix over earlier chunks: lane reads its expert's 32 counts (contig)
  const int4* cp = (const int4*)(cntT + ((size_t)b * 64 + e) * 32);
  int prefix = 0;
#pragma unroll
  for (int j = 0; j < 8; ++j) {
    const int4 v = cp[j];
    const int base = 4 * j;
    prefix += ((base + 0 < cc) ? v.x : 0) + ((base + 1 < cc) ? v.y : 0)
            + ((base + 2 < cc) ? v.z : 0) + ((base + 3 < cc) ? v.w : 0);
  }
  const float keep = (prefix + lrank < CAP) ? 1.0f : 0.0f;

#pragma unroll
  for (int j = 0; j < 64; ++j) tile[j][lane] = 0.f;
  __syncthreads();
  tile[lane][e] = keep;
  __syncthreads();

  float4*       og = (float4*)(out + (size_t)g * 64 * 64);
  const float4* ts = (const float4*)&tile[0][0];
#pragma unroll
  for (int i = 0; i < 16; ++i) og[i * 64 + lane] = ts[i * 64 + lane];

  if (g == 0) {                                 // aux loss + num_dropped
    float auxsum = 0.f; int dropped = 0;
    for (int bb = 0; bb < 8; ++bb) {
      const int4*   cq = (const int4*)  (cntT + ((size_t)bb * 64 + lane) * 32);
      const float4* pq = (const float4*)(piT  + ((size_t)bb * 64 + lane) * 32);
      int tot = 0; float ps = 0.f;
#pragma unroll
      for (int j = 0; j < 8; ++j) {
        const int4 v = cq[j];   tot += v.x + v.y + v.z + v.w;
        const float4 w = pq[j]; ps  += w.x + w.y + w.z + w.w;
      }
      dropped += (tot > CAP) ? (tot - CAP) : 0;
      const float fi = (float)((tot < CAP) ? tot : CAP) * (1.0f / (float)Ss);
      const float pi = ps * (1.0f / (float)Ss);
      float fp = fi * pi;
#pragma unroll
      for (int off = 32; off >= 1; off >>= 1) fp += __shfl_xor(fp, off);
      auxsum += fp;                             // all lanes hold batch sum
    }
#pragma unroll
    for (int off = 32; off >= 1; off >>= 1) dropped += __shfl_xor(dropped, off);
    if (lane == 0) {
      out[AUX_OFF] = (float)Ee * auxsum / (float)Bb;
      out[ND_OFF]  = (float)dropped;
    }
  }
}

extern "C" void kernel_launch(void* const* d_in, const int* in_sizes, int n_in,
                              void* d_out, int out_size, void* d_ws, size_t ws_size,
                              hipStream_t stream) {
  const float* H    = (const float*)d_in[0];
  const float* Wm   = (const float*)d_in[1];
  const float* bias = (const float*)d_in[2];
  float* out = (float*)d_out;
  char*  w2   = (char*) d_ws + W2_OFF;
  float* part = (float*)((char*)d_ws + PART_OFF);
  int*   cntT = (int*)  ((char*)d_ws + CNTT_OFF);
  float* piT  = (float*)((char*)d_ws + PIT_OFF);
  int*   eid  = (int*)  ((char*)d_ws + EID_OFF);

  hipLaunchKernelGGL(k0_wsplit,   dim3(128),  dim3(256), 0, stream, Wm, w2);
  hipLaunchKernelGGL(k1_gemm,     dim3(1024), dim3(256), 0, stream, H, w2, part);
  hipLaunchKernelGGL(k1b_softmax, dim3(256),  dim3(512), 0, stream,
                     part, bias, out, cntT, piT, eid);
  hipLaunchKernelGGL(k3_indices,  dim3(256),  dim3(64),  0, stream,
                     cntT, piT, eid, out);
}

// Round 15
// 90.236 us; speedup vs baseline: 1.7820x; 1.7820x over previous
//
#include <hip/hip_runtime.h>
#include <hip/hip_bf16.h>
#include <stdint.h>

#define Bb 8
#define Ss 2048
#define Dd 4096
#define Ee 64
#define CAP 40
#define M_TOK (Bb*Ss)                    // 16384 tokens
#define TOP1_OFF  (M_TOK*Ee)             // 1048576
#define PROBS_OFF (TOP1_OFF + M_TOK)     // 1064960
#define AUX_OFF   (PROBS_OFF + M_TOK*Ee) // 2113536
#define ND_OFF    (AUX_OFF + 1)

// ws byte offsets
#define W2_OFF   0u                      // 1 MB chunk-major W hi/lo
#define PART_OFF (1u<<20)                // 16 MB fp32 partials [tg][ks4][64][64]
#define CNTT_OFF (17u<<20)               // 64 KB int   cntT[b][e][32]
#define PIT_OFF  ((17u<<20) + (64u<<10)) // 64 KB float piT [b][e][32]
#define EID_OFF  ((17u<<20) + (128u<<10))// 64 KB int   eid[tok]

typedef __attribute__((ext_vector_type(8))) short short8;
typedef __attribute__((ext_vector_type(4))) float f32x4;

// pin vmem issue order across this point (IR + MIR schedulers)
#define FENCE() do {                                                          \
    asm volatile("" ::: "memory");                                            \
    __builtin_amdgcn_sched_barrier(0);                                        \
  } while (0)

__device__ __forceinline__ void cvt8hl(const float4 a, const float4 b,
                                       short8& hi, short8& lo) {
  __hip_bfloat162 h0 = __float22bfloat162_rn(make_float2(a.x, a.y));
  __hip_bfloat162 h1 = __float22bfloat162_rn(make_float2(a.z, a.w));
  __hip_bfloat162 h2 = __float22bfloat162_rn(make_float2(b.x, b.y));
  __hip_bfloat162 h3 = __float22bfloat162_rn(make_float2(b.z, b.w));
  float2 f0 = __bfloat1622float2(h0), f1 = __bfloat1622float2(h1);
  float2 f2 = __bfloat1622float2(h2), f3 = __bfloat1622float2(h3);
  __hip_bfloat162 l0 = __float22bfloat162_rn(make_float2(a.x - f0.x, a.y - f0.y));
  __hip_bfloat162 l1 = __float22bfloat162_rn(make_float2(a.z - f1.x, a.w - f1.y));
  __hip_bfloat162 l2 = __float22bfloat162_rn(make_float2(b.x - f2.x, b.y - f2.y));
  __hip_bfloat162 l3 = __float22bfloat162_rn(make_float2(b.z - f3.x, b.w - f3.y));
  union U { __hip_bfloat162 h[4]; short8 s; };
  U uh; uh.h[0] = h0; uh.h[1] = h1; uh.h[2] = h2; uh.h[3] = h3; hi = uh.s;
  U ul; ul.h[0] = l0; ul.h[1] = l1; ul.h[2] = l2; ul.h[3] = l3; lo = ul.s;
}

// ---- k0: W [k][e] fp32 -> chunk-major hi/lo bf16 fragments -----------------
// k32-chunk C at byte C*8192: [g(4)][hl(2)][lane(64)x16B]
__global__ __launch_bounds__(256) void k0_wsplit(const float* __restrict__ W,
                                                 char* __restrict__ w2) {
  const int id  = blockIdx.x * 256 + threadIdx.x;   // 32768 items
  const int l   = id & 63;
  const int g   = (id >> 6) & 3;
  const int sub = (id >> 8) & 1;
  const int c   = id >> 9;
  const int e   = g * 16 + (l & 15);
  const int kb  = c * 64 + sub * 32 + (l >> 4) * 8;
  float xs[8];
#pragma unroll
  for (int j = 0; j < 8; ++j) xs[j] = W[(size_t)(kb + j) * Ee + e];
  short8 hi, lo;
  cvt8hl(make_float4(xs[0], xs[1], xs[2], xs[3]),
         make_float4(xs[4], xs[5], xs[6], xs[7]), hi, lo);
  char* base = w2 + (size_t)c * 16384 + sub * 8192 + g * 2048 + l * 16;
  *(short8*)base = hi;
  *(short8*)(base + 1024) = lo;
}

// ---- k1: 64-token x K-quarter MFMA partial GEMM, QUAD-buffered (BK=32) -----
// grid 1024: tg = bid>>2, ks = bid&3. W staged 3 chunks ahead into 4x8KB LDS.
// ONE vmcnt per iter (top), retiring A(t) AND S(t+1) -- both issued 2 iters
// earlier (~600-1000 cyc cover) -> barrier carries no wait.
// Ledger (issue order per iter: S(t+3) then A(t+2); FENCE-pinned):
//   top of iter t (steady): [S(t+1),A(t) | S(t+2),A(t+1)] -> vmcnt(4)
//   retires S(t+1),A(t). Tails: t=30 -> vmcnt(2), t=31 -> vmcnt(0).
//   buf[(t+3)&3] written by S(t+3) was last read iter t-1 (barrier-separated).
__global__ __launch_bounds__(256, 4) void k1_gemm(
    const float* __restrict__ H, const char* __restrict__ w2,
    float* __restrict__ part) {
  __shared__ char wb[4][8192];
  const int tid = threadIdx.x;
  const int wv = tid >> 6, l = tid & 63;
  const int tg = blockIdx.x >> 2, ks = blockIdx.x & 3;
  const float* hA = H + (size_t)(tg * 64 + wv * 16 + (l & 15)) * Dd
                      + ks * 1024 + (l >> 4) * 8;
  const char* wsrc = w2 + (size_t)ks * 262144 + wv * 2048 + l * 16;

  f32x4 acc[4];
#pragma unroll
  for (int g = 0; g < 4; ++g) acc[g] = (f32x4){0.f, 0.f, 0.f, 0.f};

  float4 aX0, aX1, aY0, aY1;                       // depth-2 A prefetch
  short8 ah0, al0;

#define GLL16(gs, ls)                                                         \
  __builtin_amdgcn_global_load_lds(                                           \
      (const __attribute__((address_space(1))) unsigned int*)(gs),            \
      (__attribute__((address_space(3))) unsigned int*)(ls), 16, 0, 0)

#define STAGE(t, bi) {                                                        \
    const char* s_ = wsrc + (size_t)(t) * 8192;                               \
    char* d_ = &wb[bi][wv * 2048];                                            \
    GLL16(s_, d_); GLL16(s_ + 1024, d_ + 1024); }

#define LDA(r0, r1, t) { const float* p_ = hA + (t) * 32;                     \
    r0 = *(const float4*)(p_); r1 = *(const float4*)(p_ + 4); }

#define MFMA4(ac, ah, al, wh, wl) {                                           \
    ac = __builtin_amdgcn_mfma_f32_16x16x32_bf16(ah, wh, ac, 0, 0, 0);        \
    ac = __builtin_amdgcn_mfma_f32_16x16x32_bf16(ah, wl, ac, 0, 0, 0);        \
    ac = __builtin_amdgcn_mfma_f32_16x16x32_bf16(al, wh, ac, 0, 0, 0);        \
    ac = __builtin_amdgcn_mfma_f32_16x16x32_bf16(al, wl, ac, 0, 0, 0); }

#define COMPM(bi) { const char* wp_ = &wb[bi][0] + l * 16;                    \
    _Pragma("unroll")                                                         \
    for (int g = 0; g < 4; ++g) {                                             \
      const short8 wh = *(const short8*)(wp_ + g * 2048);                     \
      const short8 wl = *(const short8*)(wp_ + g * 2048 + 1024);              \
      MFMA4(acc[g], ah0, al0, wh, wl);                                        \
    } }

  // prologue: buf0 staged + published; then queue = [S(1),A(0),S(2),A(1)]
  STAGE(0, 0);
  FENCE();
  asm volatile("s_waitcnt vmcnt(0)" ::: "memory");
  __builtin_amdgcn_s_barrier();
  STAGE(1, 1);
  FENCE();
  LDA(aX0, aX1, 0);
  FENCE();
  STAGE(2, 2);
  FENCE();
  LDA(aY0, aY1, 1);
  FENCE();

#pragma unroll
  for (int t = 0; t < 32; ++t) {
    // single wait per iter: retires A(t) and S(t+1), both 2 iters old
    if (t < 30)       { asm volatile("s_waitcnt vmcnt(4)" ::: "memory"); }
    else if (t == 30) { asm volatile("s_waitcnt vmcnt(2)" ::: "memory"); }
    else              { asm volatile("s_waitcnt vmcnt(0)" ::: "memory"); }
    FENCE();
    if ((t & 1) == 0) { cvt8hl(aX0, aX1, ah0, al0); }
    else              { cvt8hl(aY0, aY1, ah0, al0); }
    FENCE();
    if (t <= 28) STAGE(t + 3, (t + 3) & 3);          // issued first (older)
    FENCE();
    if (t <= 29) {
      if ((t & 1) == 0) { LDA(aX0, aX1, t + 2); }    // issued last (newest)
      else              { LDA(aY0, aY1, t + 2); }
    }
    FENCE();
    COMPM(t & 3);
    if (t < 31) __builtin_amdgcn_s_barrier();        // no wait attached
  }

  // partial logits -> ws (fp32), [tg][ks][tok64][e]
  float* pp = part + (size_t)(tg * 4 + ks) * 4096;
#pragma unroll
  for (int g = 0; g < 4; ++g)
#pragma unroll
    for (int r = 0; r < 4; ++r)
      pp[(wv * 16 + (l >> 4) * 4 + r) * 64 + g * 16 + (l & 15)] = acc[g][r];
}

// ---- k1b: sum 4 k-partials + bias, softmax, argmax, chunk stats ------------
__global__ __launch_bounds__(512) void k1b_softmax(
    const float* __restrict__ part, const float* __restrict__ bias,
    float* __restrict__ out, int* __restrict__ cntT, float* __restrict__ piT,
    int* __restrict__ eid_ws) {
  __shared__ int   csh[512];
  __shared__ float psh[512];
  const int tid = threadIdx.x, wv = tid >> 6, l = tid & 63;
  const int tg = blockIdx.x;
  const float* p0 = part + (size_t)tg * 16384;

  int cnt = 0; float pis = 0.f;
  const float bl_ = bias[l];
#pragma unroll
  for (int i = 0; i < 8; ++i) {                 // wave owns 8 tokens
    const int t = wv * 8 + i, tok = tg * 64 + t;
    const float v = p0[t * 64 + l] + p0[4096 + t * 64 + l] +
                    p0[8192 + t * 64 + l] + p0[12288 + t * 64 + l] + bl_;
    float m = v; int mi = l;
#pragma unroll
    for (int off = 32; off >= 1; off >>= 1) {   // max + first-index argmax
      const float ov = __shfl_xor(m, off);
      const int   oi = __shfl_xor(mi, off);
      if (ov > m || (ov == m && oi < mi)) { m = ov; mi = oi; }
    }
    const float ex = __expf(v - m);
    float ssum = ex;
#pragma unroll
    for (int off = 32; off >= 1; off >>= 1) ssum += __shfl_xor(ssum, off);
    const float inv = 1.0f / ssum;
    const float p = ex * inv;
    out[(size_t)PROBS_OFF + (size_t)tok * Ee + l] = p;
    if (l == 0) {
      out[TOP1_OFF + tok] = inv;                // max prob = 1/sum
      eid_ws[tok] = mi;
    }
    cnt += (mi == l) ? 1 : 0;
    pis += p;
  }
  csh[wv * 64 + l] = cnt;
  psh[wv * 64 + l] = pis;
  __syncthreads();
  if (tid < 64) {
    int ct = 0; float pp = 0.f;
#pragma unroll
    for (int w = 0; w < 8; ++w) { ct += csh[w * 64 + tid]; pp += psh[w * 64 + tid]; }
    cntT[((size_t)(tg >> 5) * 64 + tid) * 32 + (tg & 31)] = ct;
    piT [((size_t)(tg >> 5) * 64 + tid) * 32 + (tg & 31)] = pp;
  }
}

// ---- k3: capacity mask (inline prefix) + one-hot write + aux/dropped -------
__global__ __launch_bounds__(64) void k3_indices(
    const int* __restrict__ cntT, const float* __restrict__ piT,
    const int* __restrict__ eid_ws, float* __restrict__ out) {
  __shared__ float tile[64][64];
  const int g = blockIdx.x, lane = threadIdx.x; // 64-token chunk
  const int b = g >> 5, cc = g & 31;
  const int tok = g * 64 + lane;
  const int e = eid_ws[tok];

  unsigned long long mymask = 0ull;             // same-expert mask in chunk
  for (int j = 0; j < 64; ++j) {
    const int ej = __shfl(e, j);
    const unsigned long long bal = __ballot(ej == e);
    if (j == lane) mymask = bal;
  }
  const int lrank = __popcll(mymask & ((1ull << lane) - 1ull));

  // prefix over earlier chunks: lane reads its expert's 32 counts (contig)
  const int4* cp = (const int4*)(cntT + ((size_t)b * 64 + e) * 32);
  int prefix = 0;
#pragma unroll
  for (int j = 0; j < 8; ++j) {
    const int4 v = cp[j];
    const int base = 4 * j;
    prefix += ((base + 0 < cc) ? v.x : 0) + ((base + 1 < cc) ? v.y : 0)
            + ((base + 2 < cc) ? v.z : 0) + ((base + 3 < cc) ? v.w : 0);
  }
  const float keep = (prefix + lrank < CAP) ? 1.0f : 0.0f;

#pragma unroll
  for (int j = 0; j < 64; ++j) tile[j][lane] = 0.f;
  __syncthreads();
  tile[lane][e] = keep;
  __syncthreads();

  float4*       og = (float4*)(out + (size_t)g * 64 * 64);
  const float4* ts = (const float4*)&tile[0][0];
#pragma unroll
  for (int i = 0; i < 16; ++i) og[i * 64 + lane] = ts[i * 64 + lane];

  if (g == 0) {                                 // aux loss + num_dropped
    float auxsum = 0.f; int dropped = 0;
    for (int bb = 0; bb < 8; ++bb) {
      const int4*   cq = (const int4*)  (cntT + ((size_t)bb * 64 + lane) * 32);
      const float4* pq = (const float4*)(piT  + ((size_t)bb * 64 + lane) * 32);
      int tot = 0; float ps = 0.f;
#pragma unroll
      for (int j = 0; j < 8; ++j) {
        const int4 v = cq[j];   tot += v.x + v.y + v.z + v.w;
        const float4 w = pq[j]; ps  += w.x + w.y + w.z + w.w;
      }
      dropped += (tot > CAP) ? (tot - CAP) : 0;
      const float fi = (float)((tot < CAP) ? tot : CAP) * (1.0f / (float)Ss);
      const float pi = ps * (1.0f / (float)Ss);
      float fp = fi * pi;
#pragma unroll
      for (int off = 32; off >= 1; off >>= 1) fp += __shfl_xor(fp, off);
      auxsum += fp;                             // all lanes hold batch sum
    }
#pragma unroll
    for (int off = 32; off >= 1; off >>= 1) dropped += __shfl_xor(dropped, off);
    if (lane == 0) {
      out[AUX_OFF] = (float)Ee * auxsum / (float)Bb;
      out[ND_OFF]  = (float)dropped;
    }
  }
}

extern "C" void kernel_launch(void* const* d_in, const int* in_sizes, int n_in,
                              void* d_out, int out_size, void* d_ws, size_t ws_size,
                              hipStream_t stream) {
  const float* H    = (const float*)d_in[0];
  const float* Wm   = (const float*)d_in[1];
  const float* bias = (const float*)d_in[2];
  float* out = (float*)d_out;
  char*  w2   = (char*) d_ws + W2_OFF;
  float* part = (float*)((char*)d_ws + PART_OFF);
  int*   cntT = (int*)  ((char*)d_ws + CNTT_OFF);
  float* piT  = (float*)((char*)d_ws + PIT_OFF);
  int*   eid  = (int*)  ((char*)d_ws + EID_OFF);

  hipLaunchKernelGGL(k0_wsplit,   dim3(128),  dim3(256), 0, stream, Wm, w2);
  hipLaunchKernelGGL(k1_gemm,     dim3(1024), dim3(256), 0, stream, H, w2, part);
  hipLaunchKernelGGL(k1b_softmax, dim3(256),  dim3(512), 0, stream,
                     part, bias, out, cntT, piT, eid);
  hipLaunchKernelGGL(k3_indices,  dim3(256),  dim3(64),  0, stream,
                     cntT, piT, eid, out);
}